// Round 2
// baseline (621.656 us; speedup 1.0000x reference)
//
#include <hip/hip_runtime.h>
#include <hip/hip_bf16.h>
#include <cstdint>
#include <cstddef>

typedef __bf16 bf16x8 __attribute__((ext_vector_type(8)));
typedef float  f32x4  __attribute__((ext_vector_type(4)));

static __device__ __forceinline__ float bf2f(unsigned short u){
  unsigned v = ((unsigned)u) << 16;
  return __builtin_bit_cast(float, v);
}
static __device__ __forceinline__ unsigned short f2bf_bits(float f){
  __bf16 h = (__bf16)f;
  return __builtin_bit_cast(unsigned short, h);
}

// raw barrier: drain LDS ops only; global loads stay in flight (no vmcnt(0)!)
#define KBAR() do{ asm volatile("s_waitcnt lgkmcnt(0)" ::: "memory"); \
                   __builtin_amdgcn_s_barrier(); \
                   __builtin_amdgcn_sched_barrier(0); }while(0)

// ---------------- K0a: build St[s][n] = (sum_e w(s->n)) / max(cnt[n],1) -------
__global__ __launch_bounds__(1024) void k_build_S(const int* __restrict__ ei,
                                                  const float* __restrict__ ea,
                                                  int E, float* __restrict__ St){
  __shared__ float Ssh[40000];
  __shared__ float csh[200];
  __shared__ int nzsh;
  const int t = threadIdx.x;
  if (t == 0) nzsh = 0;
  for (int i = t; i < 40000; i += 1024) Ssh[i] = 0.f;
  if (t < 200) csh[t] = 0.f;
  __syncthreads();
  // parallel int64-vs-int32 detect: int64 -> every odd int32 word is 0
  if (t < 256){ if (ei[2*t + 1] != 0) atomicOr(&nzsh, 1); }
  __syncthreads();
  const int is64 = (nzsh == 0);
  for (int e = t; e < E; e += 1024){
    int s, d;
    if (is64){ s = ei[2*e]; d = ei[2*(E+e)]; }
    else     { s = ei[e];   d = ei[E+e];     }
    if ((unsigned)s < 200u && (unsigned)d < 200u){
      atomicAdd(&Ssh[s*200 + d], ea[e]);
      atomicAdd(&csh[d], 1.f);
    }
  }
  __syncthreads();
  for (int i = t; i < 40000; i += 1024){
    int n = i % 200;
    St[i] = Ssh[i] / fmaxf(csh[n], 1.f);
  }
}

// ---------------- K0b: x (f32) -> Xb (bf16, 256 rows, XOR-swizzled layout) ----
__global__ __launch_bounds__(256) void k_xb(const float* __restrict__ x,
                                            unsigned char* __restrict__ Xb){
  int idx0 = blockIdx.x*256 + threadIdx.x;
  for (int idx = idx0; idx < 256*2048; idx += 256*256){
    int r  = idx >> 11;
    int sl = idx & 2047;
    int kc = sl >> 3, s = sl & 7;
    float4 v0 = {0.f,0.f,0.f,0.f}, v1 = {0.f,0.f,0.f,0.f};
    if (r < 200){
      const float* p = x + (size_t)r*16384 + kc*64 + s*8;
      v0 = *(const float4*)p;
      v1 = *(const float4*)(p + 4);
    }
    union { uint4 u; __bf16 h[8]; } pk;
    pk.h[0]=(__bf16)v0.x; pk.h[1]=(__bf16)v0.y; pk.h[2]=(__bf16)v0.z; pk.h[3]=(__bf16)v0.w;
    pk.h[4]=(__bf16)v1.x; pk.h[5]=(__bf16)v1.y; pk.h[6]=(__bf16)v1.z; pk.h[7]=(__bf16)v1.w;
    *(uint4*)(Xb + (size_t)r*32768 + kc*128 + ((s ^ (r & 7)) << 4)) = pk.u;
  }
}

// ---------------- GEMM: Cpart[ks][224][NOUT] (bf16) = A(224 x K) * [Wl;Wr]^T ---
// 2-deep register-staged pipeline, raw s_barrier (no vmcnt drain), hand-unrolled x2.
template<int BN, int KSPLIT, int KDIM, int NOUT, int NITER>
__global__ __launch_bounds__(512, 2) void k_gemm(const unsigned char* __restrict__ Asrc,
                                                 const float* __restrict__ Wl,
                                                 const float* __restrict__ Wr,
                                                 unsigned short* __restrict__ Cpart){
  constexpr int ROWB   = KDIM * 2;
  constexpr int BBYTES = BN * 128;
  constexpr int STAGE  = 32768 + BBYTES;
  constexpr int NL     = BN / 32;
  constexpr int NSTR   = BN / 64;
  constexpr int NT2    = (NOUT/2) / BN;
  __shared__ unsigned char smem[2*STAGE];

  const int tid = threadIdx.x;
  const int bid = blockIdx.x;
  const int ks    = bid & (KSPLIT - 1);   // same ks per XCD -> A slice L2-resident
  const int ntile = bid / KSPLIT;
  const float* W = (ntile < NT2) ? (Wl + (size_t)ntile*BN*KDIM)
                                 : (Wr + (size_t)(ntile - NT2)*BN*KDIM);
  const int kc0 = ks * NITER;

  // two named register sets (no runtime indexing -> no scratch)
  uint4  aR0[4], aR1[4];
  float4 bR0[NL], bR1[NL];

  const unsigned char* Abase = Asrc + (size_t)(tid >> 3)*ROWB + (tid & 7)*16;
  const float*         Wbase = W + (size_t)(tid >> 4)*KDIM + (tid & 15)*4;

  auto issueA = [&](uint4* aR, int kc){
    const unsigned char* p = Abase + (size_t)kc*128;
    #pragma unroll
    for (int i = 0; i < 4; i++)
      aR[i] = *(const uint4*)(p + (size_t)i*64*ROWB);
  };
  auto issueB = [&](float4* bR, int kc){
    const float* p = Wbase + (size_t)kc*64;
    #pragma unroll
    for (int L = 0; L < NL; L++)
      bR[L] = *(const float4*)(p + (size_t)L*32*KDIM);
  };
  auto writeA = [&](unsigned char* Ab, const uint4* aR){
    #pragma unroll
    for (int i = 0; i < 4; i++)
      *(uint4*)(Ab + i*8192 + tid*16) = aR[i];
  };
  auto writeB = [&](unsigned char* Bb, const float4* bR){
    #pragma unroll
    for (int L = 0; L < NL; L++){
      int c = L*8192 + tid*16;
      int o = c >> 8;
      int kb = c & 255;
      int slot = kb >> 5;
      int rem8 = (kb >> 1) & 15;
      union { uint2 u; __bf16 h[4]; } p;
      p.h[0] = (__bf16)bR[L].x; p.h[1] = (__bf16)bR[L].y;
      p.h[2] = (__bf16)bR[L].z; p.h[3] = (__bf16)bR[L].w;
      *(uint2*)(Bb + o*128 + (((slot ^ (o & 7)) << 4) | rem8)) = p.u;
    }
  };

  const int lane = tid & 63;
  const int wid  = tid >> 6;
  const int mg   = wid >> 2;
  const int ng   = wid & 3;
  const int l15  = lane & 15;
  const int sx0  = (((lane >> 4) ^ (lane & 7)) << 4);
  const int sx1  = ((((lane >> 4) + 4) ^ (lane & 7)) << 4);
  const int mbase = mg * 112;
  const int nbase = ng * (BN/4);

  f32x4 acc[7][NSTR];
  #pragma unroll
  for (int mt = 0; mt < 7; mt++)
    #pragma unroll
    for (int ns = 0; ns < NSTR; ns++)
      acc[mt][ns] = (f32x4){0.f,0.f,0.f,0.f};

  auto compute = [&](const unsigned char* buf){
    const unsigned char* Ab = buf;
    const unsigned char* Bb = buf + 32768;
    #pragma unroll
    for (int kst = 0; kst < 2; kst++){
      const int sx = kst ? sx1 : sx0;
      bf16x8 bf[NSTR];
      #pragma unroll
      for (int ns = 0; ns < NSTR; ns++)
        bf[ns] = *(const bf16x8*)(Bb + (nbase + ns*16 + l15)*128 + sx);
      #pragma unroll
      for (int mt = 0; mt < 7; mt++){
        bf16x8 af = *(const bf16x8*)(Ab + (mbase + mt*16 + l15)*128 + sx);
        #pragma unroll
        for (int ns = 0; ns < NSTR; ns++)
          acc[mt][ns] = __builtin_amdgcn_mfma_f32_16x16x32_bf16(af, bf[ns], acc[mt][ns], 0, 0, 0);
      }
    }
  };

  unsigned char* buf0 = smem;
  unsigned char* buf1 = smem + STAGE;

  // prologue: issue stages 0,1; stage buf0; barrier. Set1 loads stay in flight.
  issueA(aR0, kc0);     issueB(bR0, kc0);
  issueA(aR1, kc0 + 1); issueB(bR1, kc0 + 1);
  writeA(buf0, aR0); writeB(buf0 + 32768, bR0);   // compiler: vmcnt(12) (keeps set1 in flight)
  KBAR();

  // main loop: iter i computes buf[i&1]; issues stage i+2; stages buf[(i+1)&1]
  for (int ii = 0; ii < NITER; ii += 2){
    // ---- iter ii (even): cur=buf0, issue into set0, write set1->buf1 ----
    if (ii + 2 < NITER){ issueA(aR0, kc0 + ii + 2); issueB(bR0, kc0 + ii + 2); }
    __builtin_amdgcn_sched_barrier(0);
    compute(buf0);
    if (ii + 1 < NITER){
      writeA(buf1, aR1); writeB(buf1 + 32768, bR1);
      KBAR();
    }
    // ---- iter ii+1 (odd): cur=buf1, issue into set1, write set0->buf0 ----
    if (ii + 1 < NITER){
      if (ii + 3 < NITER){ issueA(aR1, kc0 + ii + 3); issueB(bR1, kc0 + ii + 3); }
      __builtin_amdgcn_sched_barrier(0);
      compute(buf1);
      if (ii + 2 < NITER){
        writeA(buf0, aR0); writeB(buf0 + 32768, bR0);
        KBAR();
      }
    }
  }

  // epilogue: bf16 partial store
  const int rbase = ks * 224;
  #pragma unroll
  for (int mt = 0; mt < 7; mt++)
    #pragma unroll
    for (int ns = 0; ns < NSTR; ns++)
      #pragma unroll
      for (int j = 0; j < 4; j++){
        int row = mbase + mt*16 + (lane >> 4)*4 + j;
        int col = ntile*BN + nbase + ns*16 + l15;
        Cpart[(size_t)(rbase + row)*NOUT + col] = f2bf_bits(acc[mt][ns][j]);
      }
}

// ---------------- reduce K partials (bf16) -> f32 ------------------------------
template<int KS>
__global__ __launch_bounds__(256) void k_reduce(const unsigned short* __restrict__ cp,
                                                float* __restrict__ out, int n8){
  const size_t part = (size_t)n8 * 8;
  int stride = gridDim.x * blockDim.x;
  for (int idx = blockIdx.x*blockDim.x + threadIdx.x; idx < n8; idx += stride){
    float a[8] = {0.f,0.f,0.f,0.f,0.f,0.f,0.f,0.f};
    #pragma unroll
    for (int ksi = 0; ksi < KS; ksi++){
      union { uint4 v; unsigned short s[8]; } u;
      u.v = *(const uint4*)(cp + ksi*part + (size_t)idx*8);
      #pragma unroll
      for (int j = 0; j < 8; j++) a[j] += bf2f(u.s[j]);
    }
    float4 lo = {a[0],a[1],a[2],a[3]};
    float4 hi = {a[4],a[5],a[6],a[7]};
    *(float4*)(out + (size_t)idx*8)     = lo;
    *(float4*)(out + (size_t)idx*8 + 4) = hi;
  }
}

// ---------------- h1 = relu(S@P + Q + b1) -> H1b (swizzled bf16) ---------------
__global__ __launch_bounds__(256) void k_h1(const float* __restrict__ PQ,
                                            const float* __restrict__ St,
                                            const float* __restrict__ b1,
                                            unsigned char* __restrict__ H1b){
  const int och = blockIdx.x >> 2, nsp = blockIdx.x & 3;
  const int w = threadIdx.x >> 6, lane = threadIdx.x & 63;
  const int o = och*64 + lane;
  const int nb = __builtin_amdgcn_readfirstlane(nsp*50 + w*13);
  const int ncnt = (w == 3) ? 11 : 13;
  float acc[13];
  #pragma unroll
  for (int i = 0; i < 13; i++) acc[i] = 0.f;
  for (int s = 0; s < 200; s++){
    float p = PQ[(size_t)s*8192 + o];
    #pragma unroll
    for (int i = 0; i < 13; i++)
      if (i < ncnt) acc[i] = fmaf(St[s*200 + nb + i], p, acc[i]);
  }
  float bo = b1[o];
  #pragma unroll
  for (int i = 0; i < 13; i++)
    if (i < ncnt){
      int r = nb + i;
      float h = acc[i] + PQ[(size_t)r*8192 + 4096 + o] + bo;
      h = fmaxf(h, 0.f);
      int kc = o >> 6, wi = o & 63, slot = wi >> 3, rem = wi & 7;
      *(__bf16*)(H1b + (size_t)r*8192 + kc*128 + (((slot ^ (r & 7)) << 4) | (rem*2))) = (__bf16)h;
    }
}

// ---------------- h2 = S@R + T + b2 (no relu) ----------------------------------
__global__ __launch_bounds__(256) void k_h2(const float* __restrict__ RT,
                                            const float* __restrict__ St,
                                            const float* __restrict__ b2,
                                            float* __restrict__ h2){
  const int cch = blockIdx.x >> 2, nsp = blockIdx.x & 3;
  const int w = threadIdx.x >> 6, lane = threadIdx.x & 63;
  const int c = cch*64 + lane;
  const int nb = __builtin_amdgcn_readfirstlane(nsp*50 + w*13);
  const int ncnt = (w == 3) ? 11 : 13;
  float acc[13];
  #pragma unroll
  for (int i = 0; i < 13; i++) acc[i] = 0.f;
  for (int s = 0; s < 200; s++){
    float r = RT[(size_t)s*1024 + c];
    #pragma unroll
    for (int i = 0; i < 13; i++)
      if (i < ncnt) acc[i] = fmaf(St[s*200 + nb + i], r, acc[i]);
  }
  float bc = b2[c];
  #pragma unroll
  for (int i = 0; i < 13; i++)
    if (i < ncnt){
      int n = nb + i;
      h2[(size_t)n*512 + c] = acc[i] + RT[(size_t)n*1024 + 512 + c] + bc;
    }
}

// ---------------- classifier: out[512,10] = mlp(h2^T) --------------------------
__global__ __launch_bounds__(512) void k_cls(const float* __restrict__ h2,
    const float* __restrict__ Wc1, const float* __restrict__ bc1,
    const float* __restrict__ Wc2, const float* __restrict__ bc2,
    const float* __restrict__ Wc3, const float* __restrict__ bc3,
    float* __restrict__ out){
  __shared__ float zt[64*201];
  __shared__ float z1[64*101];
  __shared__ float z2[64*51];
  const int cb = blockIdx.x * 64;
  const int t = threadIdx.x;
  for (int idx = t; idx < 64*200; idx += 512){
    int n = idx >> 6, cl = idx & 63;
    zt[cl*201 + n] = h2[(size_t)n*512 + cb + cl];
  }
  __syncthreads();
  const int w = t >> 6, c = t & 63;
  {
    const int jb = __builtin_amdgcn_readfirstlane(w*13);
    const int jn = (w == 7) ? 9 : 13;
    float a[13];
    #pragma unroll
    for (int j = 0; j < 13; j++) a[j] = (j < jn) ? bc1[jb + j] : 0.f;
    for (int n = 0; n < 200; n++){
      float v = zt[c*201 + n];
      #pragma unroll
      for (int j = 0; j < 13; j++)
        if (j < jn) a[j] = fmaf(v, Wc1[(jb + j)*200 + n], a[j]);
    }
    #pragma unroll
    for (int j = 0; j < 13; j++)
      if (j < jn) z1[c*101 + jb + j] = fmaxf(a[j], 0.f);
  }
  __syncthreads();
  {
    const int jb = __builtin_amdgcn_readfirstlane(w*7);
    const int jn = (w == 7) ? 1 : 7;
    float a[7];
    #pragma unroll
    for (int j = 0; j < 7; j++) a[j] = (j < jn) ? bc2[jb + j] : 0.f;
    for (int n = 0; n < 100; n++){
      float v = z1[c*101 + n];
      #pragma unroll
      for (int j = 0; j < 7; j++)
        if (j < jn) a[j] = fmaf(v, Wc2[(jb + j)*100 + n], a[j]);
    }
    #pragma unroll
    for (int j = 0; j < 7; j++)
      if (j < jn) z2[c*51 + jb + j] = fmaxf(a[j], 0.f);
  }
  __syncthreads();
  if (w < 5){
    const int jb = __builtin_amdgcn_readfirstlane(w*2);
    float a[2] = { bc3[jb], bc3[jb + 1] };
    for (int n = 0; n < 50; n++){
      float v = z2[c*51 + n];
      a[0] = fmaf(v, Wc3[jb*50 + n], a[0]);
      a[1] = fmaf(v, Wc3[(jb + 1)*50 + n], a[1]);
    }
    out[(size_t)(cb + c)*10 + jb]     = a[0];
    out[(size_t)(cb + c)*10 + jb + 1] = a[1];
  }
}

// ---------------- host launch ---------------------------------------------------
extern "C" void kernel_launch(void* const* d_in, const int* in_sizes, int n_in,
                              void* d_out, int out_size, void* d_ws, size_t ws_size,
                              hipStream_t stream){
  (void)n_in; (void)out_size; (void)ws_size;
  const float* x   = (const float*)d_in[0];
  const int*   ei  = (const int*)  d_in[1];
  const float* ea  = (const float*)d_in[2];
  const float* W1l = (const float*)d_in[3];
  const float* W1r = (const float*)d_in[4];
  const float* b1  = (const float*)d_in[5];
  const float* W2l = (const float*)d_in[6];
  const float* W2r = (const float*)d_in[7];
  const float* b2  = (const float*)d_in[8];
  const float* Wc1 = (const float*)d_in[9];
  const float* bc1 = (const float*)d_in[10];
  const float* Wc2 = (const float*)d_in[11];
  const float* bc2 = (const float*)d_in[12];
  const float* Wc3 = (const float*)d_in[13];
  const float* bc3 = (const float*)d_in[14];
  float* out = (float*)d_out;
  char* ws = (char*)d_ws;
  const int E = in_sizes[1] / 2;

  constexpr size_t ST_OFF  = 0;
  constexpr size_t XB_OFF  = 262144;
  constexpr size_t CP1_OFF = XB_OFF + (size_t)256*16384*2;
  constexpr size_t PQ_OFF  = CP1_OFF + (size_t)8*224*8192*2;
  constexpr size_t H1B_OFF = PQ_OFF + (size_t)224*8192*4;
  constexpr size_t CP2_OFF = H1B_OFF + (size_t)256*4096*2;
  constexpr size_t RT_OFF  = CP2_OFF + (size_t)16*224*1024*2;
  constexpr size_t H2_OFF  = RT_OFF + (size_t)224*1024*4;

  float*          St  = (float*)(ws + ST_OFF);
  unsigned char*  Xb  = (unsigned char*)(ws + XB_OFF);
  unsigned short* Cp1 = (unsigned short*)(ws + CP1_OFF);
  float*          PQ  = (float*)(ws + PQ_OFF);
  unsigned char*  H1b = (unsigned char*)(ws + H1B_OFF);
  unsigned short* Cp2 = (unsigned short*)(ws + CP2_OFF);
  float*          RT  = (float*)(ws + RT_OFF);
  float*          h2  = (float*)(ws + H2_OFF);

  k_build_S<<<dim3(1),   dim3(1024), 0, stream>>>(ei, ea, E, St);
  k_xb     <<<dim3(256), dim3(256),  0, stream>>>(x, Xb);
  k_gemm<256, 8, 16384, 8192, 32><<<dim3(256), dim3(512), 0, stream>>>(Xb, W1l, W1r, Cp1);
  k_reduce<8> <<<dim3(256), dim3(256), 0, stream>>>(Cp1, PQ, 224*8192/8);
  k_h1     <<<dim3(256), dim3(256),  0, stream>>>(PQ, St, b1, H1b);
  k_gemm<64, 16, 4096, 1024, 4><<<dim3(256), dim3(512), 0, stream>>>(H1b, W2l, W2r, Cp2);
  k_reduce<16><<<dim3(64), dim3(256), 0, stream>>>(Cp2, RT, 224*1024/8);
  k_h2     <<<dim3(32),  dim3(256),  0, stream>>>(RT, St, b2, h2);
  k_cls    <<<dim3(8),   dim3(512),  0, stream>>>(h2, Wc1, bc1, Wc2, bc2, Wc3, bc3, out);
}

// Round 3
// 507.767 us; speedup vs baseline: 1.2243x; 1.2243x over previous
//
#include <hip/hip_runtime.h>
#include <hip/hip_bf16.h>
#include <cstdint>
#include <cstddef>

typedef __bf16 bf16x8 __attribute__((ext_vector_type(8)));
typedef float  f32x4  __attribute__((ext_vector_type(4)));

typedef const __attribute__((address_space(1))) unsigned int gu32;
typedef __attribute__((address_space(3))) unsigned int lu32;

static __device__ __forceinline__ float bf2f(unsigned short u){
  unsigned v = ((unsigned)u) << 16;
  return __builtin_bit_cast(float, v);
}
static __device__ __forceinline__ unsigned short f2bf_bits(float f){
  __bf16 h = (__bf16)f;
  return __builtin_bit_cast(unsigned short, h);
}

// ---------------- K0a: build St[s][n] = (sum_e w(s->n)) / max(cnt[n],1) -------
__global__ __launch_bounds__(1024) void k_build_S(const int* __restrict__ ei,
                                                  const float* __restrict__ ea,
                                                  int E, float* __restrict__ St){
  __shared__ float Ssh[40000];
  __shared__ float csh[200];
  __shared__ int nzsh;
  const int t = threadIdx.x;
  if (t == 0) nzsh = 0;
  for (int i = t; i < 40000; i += 1024) Ssh[i] = 0.f;
  if (t < 200) csh[t] = 0.f;
  __syncthreads();
  if (t < 256){ if (ei[2*t + 1] != 0) atomicOr(&nzsh, 1); }
  __syncthreads();
  const int is64 = (nzsh == 0);
  for (int e = t; e < E; e += 1024){
    int s, d;
    if (is64){ s = ei[2*e]; d = ei[2*(E+e)]; }
    else     { s = ei[e];   d = ei[E+e];     }
    if ((unsigned)s < 200u && (unsigned)d < 200u){
      atomicAdd(&Ssh[s*200 + d], ea[e]);
      atomicAdd(&csh[d], 1.f);
    }
  }
  __syncthreads();
  for (int i = t; i < 40000; i += 1024){
    int n = i % 200;
    St[i] = Ssh[i] / fmaxf(csh[n], 1.f);
  }
}

// ---------------- K0b: x (f32) -> Xb (bf16, 256 rows, XOR-swizzled layout) ----
// byte(r,k) = r*32768 + (k/64)*128 + ((slot ^ (r&7))*16 + (k%8)*2, slot=(k%64)/8
__global__ __launch_bounds__(256) void k_xb(const float* __restrict__ x,
                                            unsigned char* __restrict__ Xb){
  int idx0 = blockIdx.x*256 + threadIdx.x;
  for (int idx = idx0; idx < 256*2048; idx += 256*256){
    int r  = idx >> 11;
    int sl = idx & 2047;
    int kc = sl >> 3, s = sl & 7;
    float4 v0 = {0.f,0.f,0.f,0.f}, v1 = {0.f,0.f,0.f,0.f};
    if (r < 200){
      const float* p = x + (size_t)r*16384 + kc*64 + s*8;
      v0 = *(const float4*)p;
      v1 = *(const float4*)(p + 4);
    }
    union { uint4 u; __bf16 h[8]; } pk;
    pk.h[0]=(__bf16)v0.x; pk.h[1]=(__bf16)v0.y; pk.h[2]=(__bf16)v0.z; pk.h[3]=(__bf16)v0.w;
    pk.h[4]=(__bf16)v1.x; pk.h[5]=(__bf16)v1.y; pk.h[6]=(__bf16)v1.z; pk.h[7]=(__bf16)v1.w;
    *(uint4*)(Xb + (size_t)r*32768 + kc*128 + ((s ^ (r & 7)) << 4)) = pk.u;
  }
}

// ---------------- GEMM: Cpart[ks][224][NOUT] = A(224 x K) * [Wl;Wr]^T ----------
// Per-wave column ownership: wave w owns cols [w*BN/8, (w+1)*BN/8), all 224 rows.
// B: global f32 -> regs -> cvt -> MFMA operand (never LDS). A: global_load_lds.
// Counted vmcnt: NB B-loads always in flight; single raw barrier per stage.
template<int BN, int KSPLIT, int KDIM, int NOUT, int NITER>
__global__ __launch_bounds__(512, 2) void k_gemm(const unsigned char* __restrict__ Asrc,
                                                 const float* __restrict__ Wl,
                                                 const float* __restrict__ Wr,
                                                 unsigned short* __restrict__ Cpart){
  constexpr int ROWB = KDIM * 2;
  constexpr int NS   = BN / 128;      // 16-col strips per wave
  constexpr int NB   = NS * 4;        // B float4 loads per lane per stage
  constexpr int NT2  = (NOUT/2) / BN;
  __shared__ unsigned char bufA[2][32768];

  const int tid  = threadIdx.x;
  const int lane = tid & 63, wid = tid >> 6;
  const int l15  = lane & 15, lk = lane >> 4;
  const int bid  = blockIdx.x;
  const int ks    = bid & (KSPLIT - 1);   // same ks per XCD -> A slice L2-resident
  const int ntile = bid / KSPLIT;
  const float* W = (ntile < NT2) ? (Wl + (size_t)ntile*BN*KDIM)
                                 : (Wr + (size_t)(ntile - NT2)*BN*KDIM);
  const int kc0 = ks * NITER;

  // B addressing: lane reads W rows (wid*BN/8 + ns*16 + l15), k = kc*64+kst*32+lk*8..+7
  const float* WB = W + (size_t)(wid*(BN/8) + l15)*KDIM + lk*8;
  float4 bA[NB], bB[NB];

  auto issueB = [&](float4* b, int kc){
    const float* p = WB + (size_t)kc*64;
    #pragma unroll
    for (int ns = 0; ns < NS; ns++)
      #pragma unroll
      for (int kst = 0; kst < 2; kst++){
        const float* q = p + (size_t)ns*16*KDIM + kst*32;
        b[(ns*2+kst)*2 + 0] = *(const float4*)q;
        b[(ns*2+kst)*2 + 1] = *(const float4*)(q + 4);
      }
    __builtin_amdgcn_sched_barrier(0);
  };

  // A: linear gload_lds of pre-swizzled rows; LDS[row][slot] with slot pre-XORed.
  const unsigned char* AG = Asrc + (size_t)(tid >> 3)*ROWB + (tid & 7)*16;
  auto issueA = [&](unsigned char* bufa, int kc){
    const unsigned char* g = AG + (size_t)kc*128;
    #pragma unroll
    for (int j = 0; j < 4; j++){
      __builtin_amdgcn_global_load_lds(
          (gu32*)(g + (size_t)j*64*ROWB),
          (lu32*)(bufa + j*8192 + wid*1024),
          16, 0, 0);
    }
    __builtin_amdgcn_sched_barrier(0);
  };

  bf16x8 frag[NS*2];                 // [ns*2 + kst]
  auto cvtB = [&](const float4* b){
    #pragma unroll
    for (int f = 0; f < NS*2; f++){
      float4 lo = b[f*2], hi = b[f*2+1];
      bf16x8 v;
      v[0]=(__bf16)lo.x; v[1]=(__bf16)lo.y; v[2]=(__bf16)lo.z; v[3]=(__bf16)lo.w;
      v[4]=(__bf16)hi.x; v[5]=(__bf16)hi.y; v[6]=(__bf16)hi.z; v[7]=(__bf16)hi.w;
      frag[f] = v;
    }
  };

  const int sx0 = ((lk     ^ (l15 & 7)) << 4);
  const int sx1 = (((lk+4) ^ (l15 & 7)) << 4);

  f32x4 acc[14][NS];
  #pragma unroll
  for (int mt = 0; mt < 14; mt++)
    #pragma unroll
    for (int ns = 0; ns < NS; ns++)
      acc[mt][ns] = (f32x4){0.f,0.f,0.f,0.f};

  auto compute = [&](const unsigned char* bufa){
    #pragma unroll
    for (int kst = 0; kst < 2; kst++){
      const int sx = kst ? sx1 : sx0;
      #pragma unroll
      for (int mt = 0; mt < 14; mt++){
        bf16x8 af = *(const bf16x8*)(bufa + (mt*16 + l15)*128 + sx);
        #pragma unroll
        for (int ns = 0; ns < NS; ns++)
          acc[mt][ns] = __builtin_amdgcn_mfma_f32_16x16x32_bf16(af, frag[ns*2+kst], acc[mt][ns], 0, 0, 0);
      }
    }
  };

  auto barrier_lgkm = [&](){
    asm volatile("s_waitcnt lgkmcnt(0)" ::: "memory");
    __builtin_amdgcn_s_barrier();
    __builtin_amdgcn_sched_barrier(0);
  };
  auto wait_vm = [&](){
    if constexpr (NB == 8) asm volatile("s_waitcnt vmcnt(8)" ::: "memory");
    else                   asm volatile("s_waitcnt vmcnt(4)" ::: "memory");
    __builtin_amdgcn_sched_barrier(0);
  };

  // prologue: stage 0 loads in flight. Invariant at loop entry: [B(i) NB, A(i) 4]
  issueB(bA, kc0);
  issueA(bufA[0], kc0);

  int i = 0;
  for (; i < NITER - 2; i += 2){
    // even sub-iter: uses bA/buf0
    issueB(bB, kc0 + i + 1);
    wait_vm();                 // B(i)+A(i) done; B(i+1) stays in flight
    barrier_lgkm();            // A(i) visible to all; buf1 free to overwrite
    cvtB(bA);
    issueA(bufA[1], kc0 + i + 1);
    compute(bufA[0]);
    // odd sub-iter: uses bB/buf1
    issueB(bA, kc0 + i + 2);
    wait_vm();
    barrier_lgkm();
    cvtB(bB);
    issueA(bufA[0], kc0 + i + 2);
    compute(bufA[1]);
  }
  // peeled pair: i = NITER-2
  issueB(bB, kc0 + i + 1);
  wait_vm();
  barrier_lgkm();
  cvtB(bA);
  issueA(bufA[1], kc0 + i + 1);
  compute(bufA[0]);
  asm volatile("s_waitcnt vmcnt(0)" ::: "memory");
  __builtin_amdgcn_sched_barrier(0);
  barrier_lgkm();
  cvtB(bB);
  compute(bufA[1]);

  // epilogue: bf16 partial store. row = mt*16 + lk*4 + j, col = wave-owned strip
  const int rbase = ks * 224;
  const int cbase = ntile*BN + wid*(BN/8);
  #pragma unroll
  for (int mt = 0; mt < 14; mt++)
    #pragma unroll
    for (int ns = 0; ns < NS; ns++)
      #pragma unroll
      for (int j = 0; j < 4; j++){
        int row = mt*16 + lk*4 + j;
        int col = cbase + ns*16 + l15;
        Cpart[(size_t)(rbase + row)*NOUT + col] = f2bf_bits(acc[mt][ns][j]);
      }
}

// ---------------- reduce K partials (bf16) -> f32 ------------------------------
template<int KS>
__global__ __launch_bounds__(256) void k_reduce(const unsigned short* __restrict__ cp,
                                                float* __restrict__ out, int n8){
  const size_t part = (size_t)n8 * 8;
  int stride = gridDim.x * blockDim.x;
  for (int idx = blockIdx.x*blockDim.x + threadIdx.x; idx < n8; idx += stride){
    float a[8] = {0.f,0.f,0.f,0.f,0.f,0.f,0.f,0.f};
    #pragma unroll
    for (int ksi = 0; ksi < KS; ksi++){
      union { uint4 v; unsigned short s[8]; } u;
      u.v = *(const uint4*)(cp + ksi*part + (size_t)idx*8);
      #pragma unroll
      for (int j = 0; j < 8; j++) a[j] += bf2f(u.s[j]);
    }
    float4 lo = {a[0],a[1],a[2],a[3]};
    float4 hi = {a[4],a[5],a[6],a[7]};
    *(float4*)(out + (size_t)idx*8)     = lo;
    *(float4*)(out + (size_t)idx*8 + 4) = hi;
  }
}

// ---------------- h1 = relu(S@P + Q + b1) -> H1b (swizzled bf16) ---------------
__global__ __launch_bounds__(256) void k_h1(const float* __restrict__ PQ,
                                            const float* __restrict__ St,
                                            const float* __restrict__ b1,
                                            unsigned char* __restrict__ H1b){
  const int och = blockIdx.x >> 2, nsp = blockIdx.x & 3;
  const int w = threadIdx.x >> 6, lane = threadIdx.x & 63;
  const int o = och*64 + lane;
  const int nb = __builtin_amdgcn_readfirstlane(nsp*50 + w*13);
  const int ncnt = (w == 3) ? 11 : 13;
  float acc[13];
  #pragma unroll
  for (int i = 0; i < 13; i++) acc[i] = 0.f;
  for (int s = 0; s < 200; s++){
    float p = PQ[(size_t)s*8192 + o];
    #pragma unroll
    for (int i = 0; i < 13; i++)
      if (i < ncnt) acc[i] = fmaf(St[s*200 + nb + i], p, acc[i]);
  }
  float bo = b1[o];
  #pragma unroll
  for (int i = 0; i < 13; i++)
    if (i < ncnt){
      int r = nb + i;
      float h = acc[i] + PQ[(size_t)r*8192 + 4096 + o] + bo;
      h = fmaxf(h, 0.f);
      int kc = o >> 6, wi = o & 63, slot = wi >> 3, rem = wi & 7;
      *(__bf16*)(H1b + (size_t)r*8192 + kc*128 + (((slot ^ (r & 7)) << 4) | (rem*2))) = (__bf16)h;
    }
}

// ---------------- h2 = S@R + T + b2 (no relu) ----------------------------------
__global__ __launch_bounds__(256) void k_h2(const float* __restrict__ RT,
                                            const float* __restrict__ St,
                                            const float* __restrict__ b2,
                                            float* __restrict__ h2){
  const int cch = blockIdx.x >> 2, nsp = blockIdx.x & 3;
  const int w = threadIdx.x >> 6, lane = threadIdx.x & 63;
  const int c = cch*64 + lane;
  const int nb = __builtin_amdgcn_readfirstlane(nsp*50 + w*13);
  const int ncnt = (w == 3) ? 11 : 13;
  float acc[13];
  #pragma unroll
  for (int i = 0; i < 13; i++) acc[i] = 0.f;
  for (int s = 0; s < 200; s++){
    float r = RT[(size_t)s*1024 + c];
    #pragma unroll
    for (int i = 0; i < 13; i++)
      if (i < ncnt) acc[i] = fmaf(St[s*200 + nb + i], r, acc[i]);
  }
  float bc = b2[c];
  #pragma unroll
  for (int i = 0; i < 13; i++)
    if (i < ncnt){
      int n = nb + i;
      h2[(size_t)n*512 + c] = acc[i] + RT[(size_t)n*1024 + 512 + c] + bc;
    }
}

// ---------------- classifier: out[512,10] = mlp(h2^T) --------------------------
__global__ __launch_bounds__(512) void k_cls(const float* __restrict__ h2,
    const float* __restrict__ Wc1, const float* __restrict__ bc1,
    const float* __restrict__ Wc2, const float* __restrict__ bc2,
    const float* __restrict__ Wc3, const float* __restrict__ bc3,
    float* __restrict__ out){
  __shared__ float zt[64*201];
  __shared__ float z1[64*101];
  __shared__ float z2[64*51];
  const int cb = blockIdx.x * 64;
  const int t = threadIdx.x;
  for (int idx = t; idx < 64*200; idx += 512){
    int n = idx >> 6, cl = idx & 63;
    zt[cl*201 + n] = h2[(size_t)n*512 + cb + cl];
  }
  __syncthreads();
  const int w = t >> 6, c = t & 63;
  {
    const int jb = __builtin_amdgcn_readfirstlane(w*13);
    const int jn = (w == 7) ? 9 : 13;
    float a[13];
    #pragma unroll
    for (int j = 0; j < 13; j++) a[j] = (j < jn) ? bc1[jb + j] : 0.f;
    for (int n = 0; n < 200; n++){
      float v = zt[c*201 + n];
      #pragma unroll
      for (int j = 0; j < 13; j++)
        if (j < jn) a[j] = fmaf(v, Wc1[(jb + j)*200 + n], a[j]);
    }
    #pragma unroll
    for (int j = 0; j < 13; j++)
      if (j < jn) z1[c*101 + jb + j] = fmaxf(a[j], 0.f);
  }
  __syncthreads();
  {
    const int jb = __builtin_amdgcn_readfirstlane(w*7);
    const int jn = (w == 7) ? 1 : 7;
    float a[7];
    #pragma unroll
    for (int j = 0; j < 7; j++) a[j] = (j < jn) ? bc2[jb + j] : 0.f;
    for (int n = 0; n < 100; n++){
      float v = z1[c*101 + n];
      #pragma unroll
      for (int j = 0; j < 7; j++)
        if (j < jn) a[j] = fmaf(v, Wc2[(jb + j)*100 + n], a[j]);
    }
    #pragma unroll
    for (int j = 0; j < 7; j++)
      if (j < jn) z2[c*51 + jb + j] = fmaxf(a[j], 0.f);
  }
  __syncthreads();
  if (w < 5){
    const int jb = __builtin_amdgcn_readfirstlane(w*2);
    float a[2] = { bc3[jb], bc3[jb + 1] };
    for (int n = 0; n < 50; n++){
      float v = z2[c*51 + n];
      a[0] = fmaf(v, Wc3[jb*50 + n], a[0]);
      a[1] = fmaf(v, Wc3[(jb + 1)*50 + n], a[1]);
    }
    out[(size_t)(cb + c)*10 + jb]     = a[0];
    out[(size_t)(cb + c)*10 + jb + 1] = a[1];
  }
}

// ---------------- host launch ---------------------------------------------------
extern "C" void kernel_launch(void* const* d_in, const int* in_sizes, int n_in,
                              void* d_out, int out_size, void* d_ws, size_t ws_size,
                              hipStream_t stream){
  (void)n_in; (void)out_size; (void)ws_size;
  const float* x   = (const float*)d_in[0];
  const int*   ei  = (const int*)  d_in[1];
  const float* ea  = (const float*)d_in[2];
  const float* W1l = (const float*)d_in[3];
  const float* W1r = (const float*)d_in[4];
  const float* b1  = (const float*)d_in[5];
  const float* W2l = (const float*)d_in[6];
  const float* W2r = (const float*)d_in[7];
  const float* b2  = (const float*)d_in[8];
  const float* Wc1 = (const float*)d_in[9];
  const float* bc1 = (const float*)d_in[10];
  const float* Wc2 = (const float*)d_in[11];
  const float* bc2 = (const float*)d_in[12];
  const float* Wc3 = (const float*)d_in[13];
  const float* bc3 = (const float*)d_in[14];
  float* out = (float*)d_out;
  char* ws = (char*)d_ws;
  const int E = in_sizes[1] / 2;

  constexpr size_t ST_OFF  = 0;
  constexpr size_t XB_OFF  = 262144;
  constexpr size_t CP1_OFF = XB_OFF + (size_t)256*16384*2;
  constexpr size_t PQ_OFF  = CP1_OFF + (size_t)8*224*8192*2;
  constexpr size_t H1B_OFF = PQ_OFF + (size_t)224*8192*4;
  constexpr size_t CP2_OFF = H1B_OFF + (size_t)256*4096*2;
  constexpr size_t RT_OFF  = CP2_OFF + (size_t)16*224*1024*2;
  constexpr size_t H2_OFF  = RT_OFF + (size_t)224*1024*4;

  float*          St  = (float*)(ws + ST_OFF);
  unsigned char*  Xb  = (unsigned char*)(ws + XB_OFF);
  unsigned short* Cp1 = (unsigned short*)(ws + CP1_OFF);
  float*          PQ  = (float*)(ws + PQ_OFF);
  unsigned char*  H1b = (unsigned char*)(ws + H1B_OFF);
  unsigned short* Cp2 = (unsigned short*)(ws + CP2_OFF);
  float*          RT  = (float*)(ws + RT_OFF);
  float*          h2  = (float*)(ws + H2_OFF);

  k_build_S<<<dim3(1),   dim3(1024), 0, stream>>>(ei, ea, E, St);
  k_xb     <<<dim3(256), dim3(256),  0, stream>>>(x, Xb);
  k_gemm<256, 8, 16384, 8192, 32><<<dim3(256), dim3(512), 0, stream>>>(Xb, W1l, W1r, Cp1);
  k_reduce<8> <<<dim3(256), dim3(256), 0, stream>>>(Cp1, PQ, 224*8192/8);
  k_h1     <<<dim3(256), dim3(256),  0, stream>>>(PQ, St, b1, H1b);
  k_gemm<128, 16, 4096, 1024, 4><<<dim3(128), dim3(512), 0, stream>>>(H1b, W2l, W2r, Cp2);
  k_reduce<16><<<dim3(64), dim3(256), 0, stream>>>(Cp2, RT, 224*1024/8);
  k_h2     <<<dim3(32),  dim3(256),  0, stream>>>(RT, St, b2, h2);
  k_cls    <<<dim3(8),   dim3(512),  0, stream>>>(h2, Wc1, bc1, Wc2, bc2, Wc3, bc3, out);
}

// Round 4
// 484.041 us; speedup vs baseline: 1.2843x; 1.0490x over previous
//
#include <hip/hip_runtime.h>
#include <hip/hip_bf16.h>
#include <cstdint>
#include <cstddef>

typedef __bf16 bf16x8 __attribute__((ext_vector_type(8)));
typedef float  f32x4  __attribute__((ext_vector_type(4)));

typedef const __attribute__((address_space(1))) unsigned int gu32;
typedef __attribute__((address_space(3))) unsigned int lu32;

static __device__ __forceinline__ float bf2f(unsigned short u){
  unsigned v = ((unsigned)u) << 16;
  return __builtin_bit_cast(float, v);
}
static __device__ __forceinline__ unsigned short f2bf_bits(float f){
  __bf16 h = (__bf16)f;
  return __builtin_bit_cast(unsigned short, h);
}

// ---------------- K0a: build St[s][n] = (sum_e w(s->n)) / max(cnt[n],1) -------
__global__ __launch_bounds__(1024) void k_build_S(const int* __restrict__ ei,
                                                  const float* __restrict__ ea,
                                                  int E, float* __restrict__ St){
  __shared__ float Ssh[40000];
  __shared__ float csh[200];
  __shared__ int nzsh;
  const int t = threadIdx.x;
  if (t == 0) nzsh = 0;
  for (int i = t; i < 40000; i += 1024) Ssh[i] = 0.f;
  if (t < 200) csh[t] = 0.f;
  __syncthreads();
  if (t < 256){ if (ei[2*t + 1] != 0) atomicOr(&nzsh, 1); }
  __syncthreads();
  const int is64 = (nzsh == 0);
  for (int e = t; e < E; e += 1024){
    int s, d;
    if (is64){ s = ei[2*e]; d = ei[2*(E+e)]; }
    else     { s = ei[e];   d = ei[E+e];     }
    if ((unsigned)s < 200u && (unsigned)d < 200u){
      atomicAdd(&Ssh[s*200 + d], ea[e]);
      atomicAdd(&csh[d], 1.f);
    }
  }
  __syncthreads();
  for (int i = t; i < 40000; i += 1024){
    int n = i % 200;
    St[i] = Ssh[i] / fmaxf(csh[n], 1.f);
  }
}

// ---------------- K0b: x (f32) -> Xb (bf16, 256 rows, XOR-swizzled layout) ----
// byte(r,k) = r*32768 + (k/64)*128 + ((slot ^ (r&7))*16 + (k%8)*2, slot=(k%64)/8
__global__ __launch_bounds__(256) void k_xb(const float* __restrict__ x,
                                            unsigned char* __restrict__ Xb){
  int idx0 = blockIdx.x*256 + threadIdx.x;
  for (int idx = idx0; idx < 256*2048; idx += 256*256){
    int r  = idx >> 11;
    int sl = idx & 2047;
    int kc = sl >> 3, s = sl & 7;
    float4 v0 = {0.f,0.f,0.f,0.f}, v1 = {0.f,0.f,0.f,0.f};
    if (r < 200){
      const float* p = x + (size_t)r*16384 + kc*64 + s*8;
      v0 = *(const float4*)p;
      v1 = *(const float4*)(p + 4);
    }
    union { uint4 u; __bf16 h[8]; } pk;
    pk.h[0]=(__bf16)v0.x; pk.h[1]=(__bf16)v0.y; pk.h[2]=(__bf16)v0.z; pk.h[3]=(__bf16)v0.w;
    pk.h[4]=(__bf16)v1.x; pk.h[5]=(__bf16)v1.y; pk.h[6]=(__bf16)v1.z; pk.h[7]=(__bf16)v1.w;
    *(uint4*)(Xb + (size_t)r*32768 + kc*128 + ((s ^ (r & 7)) << 4)) = pk.u;
  }
}

// ---------------- GEMM: Cpart[ks][224][NOUT] = A(224 x K) * [Wl;Wr]^T ----------
// Per-wave column ownership (wave w owns 32/16 cols, all 224 rows).
// B: f32 -> regs -> bf16 frags (single reg set, reused). A: global_load_lds.
// Stage-top vmcnt(0)+barrier: next-stage loads issued BEFORE compute -> full
// overlap, nothing younger queued at the wait. k-phase rotation by ntile
// breaks the 64KB-row-stride HBM channel aliasing.
template<int BN, int KSPLIT, int KDIM, int NOUT, int BK>
__global__ __launch_bounds__(512, 2) void k_gemm(const unsigned char* __restrict__ Asrc,
                                                 const float* __restrict__ Wl,
                                                 const float* __restrict__ Wr,
                                                 unsigned short* __restrict__ Cpart){
  constexpr int ROWB   = KDIM * 2;
  constexpr int NITER  = KDIM / BK / KSPLIT;
  constexpr int NKST   = BK / 32;          // 2 or 4 k-sub-steps
  constexpr int NS     = BN / 128;         // 16-col strips per wave
  constexpr int NB     = NS * NKST * 2;    // float4 staging regs per lane
  constexpr int APITCH = BK * 2;           // LDS row pitch (bytes)
  constexpr int LPR    = BK / 8;           // lanes per A row (gload)
  constexpr int AJ     = BK / 16;          // gload_lds instrs per wave per stage
  constexpr int NT2    = (NOUT/2) / BN;
  __shared__ unsigned char bufA[2][256*APITCH];

  const int tid  = threadIdx.x;
  const int lane = tid & 63, wid = tid >> 6;
  const int l15  = lane & 15, lk = lane >> 4;
  const int bid  = blockIdx.x;
  const int ks    = bid & (KSPLIT - 1);   // ks == XCD id -> A slice L2-resident
  const int ntile = bid / KSPLIT;
  const float* W = (ntile < NT2) ? (Wl + (size_t)ntile*BN*KDIM)
                                 : (Wr + (size_t)(ntile - NT2)*BN*KDIM);
  const int kc0   = ks * NITER;
  const int phase = ntile & (NITER - 1);

  // B staging (one set, reused every stage after cvt)
  float4 bA[NB];
  const float* WB = W + (size_t)(wid*(BN/8) + l15)*KDIM + lk*8;

  auto issueB = [&](int kc){
    const float* p = WB + (size_t)kc*BK;
    #pragma unroll
    for (int ns = 0; ns < NS; ns++)
      #pragma unroll
      for (int kst = 0; kst < NKST; kst++){
        const float* q = p + (size_t)ns*16*KDIM + kst*32;
        bA[(ns*NKST+kst)*2 + 0] = *(const float4*)q;
        bA[(ns*NKST+kst)*2 + 1] = *(const float4*)(q + 4);
      }
    __builtin_amdgcn_sched_barrier(0);
  };

  const unsigned char* AG = Asrc + (size_t)(tid/LPR)*ROWB + (tid%LPR)*16;
  auto issueA = [&](unsigned char* bufa, int kc){
    const unsigned char* g = AG + (size_t)kc*APITCH;
    #pragma unroll
    for (int j = 0; j < AJ; j++){
      __builtin_amdgcn_global_load_lds(
          (gu32*)(g + (size_t)j*(512/LPR)*ROWB),
          (lu32*)(bufa + j*8192 + wid*1024),
          16, 0, 0);
    }
    __builtin_amdgcn_sched_barrier(0);
  };

  bf16x8 frag[NS*NKST];
  auto cvtB = [&](){
    #pragma unroll
    for (int f = 0; f < NS*NKST; f++){
      float4 lo = bA[f*2], hi = bA[f*2+1];
      bf16x8 v;
      v[0]=(__bf16)lo.x; v[1]=(__bf16)lo.y; v[2]=(__bf16)lo.z; v[3]=(__bf16)lo.w;
      v[4]=(__bf16)hi.x; v[5]=(__bf16)hi.y; v[6]=(__bf16)hi.z; v[7]=(__bf16)hi.w;
      frag[f] = v;
    }
  };

  f32x4 acc[14][NS];
  #pragma unroll
  for (int mt = 0; mt < 14; mt++)
    #pragma unroll
    for (int ns = 0; ns < NS; ns++)
      acc[mt][ns] = (f32x4){0.f,0.f,0.f,0.f};

  auto compute = [&](const unsigned char* bufa){
    #pragma unroll
    for (int kst = 0; kst < NKST; kst++){
      const int sx = (kst>>1)*128 + ((((kst&1)*4 + lk) ^ (l15 & 7)) << 4);
      #pragma unroll
      for (int mt = 0; mt < 14; mt++){
        bf16x8 af = *(const bf16x8*)(bufa + (mt*16 + l15)*APITCH + sx);
        #pragma unroll
        for (int ns = 0; ns < NS; ns++)
          acc[mt][ns] = __builtin_amdgcn_mfma_f32_16x16x32_bf16(af, frag[ns*NKST+kst], acc[mt][ns], 0, 0, 0);
      }
    }
  };

  auto kcAt = [&](int i){ return kc0 + ((i + phase) & (NITER - 1)); };

  // prologue: stage 0 loads in flight
  issueB(kcAt(0));
  issueA(bufA[0], kcAt(0));

  for (int i = 0; i < NITER; i++){
    // stage top: only stage-i loads outstanding -> vmcnt(0) drains exactly them
    asm volatile("s_waitcnt vmcnt(0) lgkmcnt(0)" ::: "memory");
    __builtin_amdgcn_s_barrier();
    __builtin_amdgcn_sched_barrier(0);
    cvtB();                                   // frags from stage i; bA freed
    if (i + 1 < NITER){
      issueB(kcAt(i + 1));                    // refill bA
      issueA(bufA[(i + 1) & 1], kcAt(i + 1)); // other LDS buffer
    }
    __builtin_amdgcn_sched_barrier(0);
    compute(bufA[i & 1]);                     // overlaps with stage i+1 loads
  }

  // epilogue: bf16 partial store
  const int rbase = ks * 224;
  const int cbase = ntile*BN + wid*(BN/8);
  #pragma unroll
  for (int mt = 0; mt < 14; mt++)
    #pragma unroll
    for (int ns = 0; ns < NS; ns++)
      #pragma unroll
      for (int j = 0; j < 4; j++){
        int row = mt*16 + lk*4 + j;
        int col = cbase + ns*16 + l15;
        Cpart[(size_t)(rbase + row)*NOUT + col] = f2bf_bits(acc[mt][ns][j]);
      }
}

// ---------------- reduce K partials (bf16) -> f32 ------------------------------
template<int KS>
__global__ __launch_bounds__(256) void k_reduce(const unsigned short* __restrict__ cp,
                                                float* __restrict__ out, int n8){
  const size_t part = (size_t)n8 * 8;
  int stride = gridDim.x * blockDim.x;
  for (int idx = blockIdx.x*blockDim.x + threadIdx.x; idx < n8; idx += stride){
    float a[8] = {0.f,0.f,0.f,0.f,0.f,0.f,0.f,0.f};
    #pragma unroll
    for (int ksi = 0; ksi < KS; ksi++){
      union { uint4 v; unsigned short s[8]; } u;
      u.v = *(const uint4*)(cp + ksi*part + (size_t)idx*8);
      #pragma unroll
      for (int j = 0; j < 8; j++) a[j] += bf2f(u.s[j]);
    }
    float4 lo = {a[0],a[1],a[2],a[3]};
    float4 hi = {a[4],a[5],a[6],a[7]};
    *(float4*)(out + (size_t)idx*8)     = lo;
    *(float4*)(out + (size_t)idx*8 + 4) = hi;
  }
}

// ---------------- h1 = relu(S@P + Q + b1) -> H1b (swizzled bf16) ---------------
__global__ __launch_bounds__(256) void k_h1(const float* __restrict__ PQ,
                                            const float* __restrict__ St,
                                            const float* __restrict__ b1,
                                            unsigned char* __restrict__ H1b){
  const int och = blockIdx.x >> 2, nsp = blockIdx.x & 3;
  const int w = threadIdx.x >> 6, lane = threadIdx.x & 63;
  const int o = och*64 + lane;
  const int nb = __builtin_amdgcn_readfirstlane(nsp*50 + w*13);
  const int ncnt = (w == 3) ? 11 : 13;
  float acc[13];
  #pragma unroll
  for (int i = 0; i < 13; i++) acc[i] = 0.f;
  for (int s = 0; s < 200; s++){
    float p = PQ[(size_t)s*8192 + o];
    #pragma unroll
    for (int i = 0; i < 13; i++)
      if (i < ncnt) acc[i] = fmaf(St[s*200 + nb + i], p, acc[i]);
  }
  float bo = b1[o];
  #pragma unroll
  for (int i = 0; i < 13; i++)
    if (i < ncnt){
      int r = nb + i;
      float h = acc[i] + PQ[(size_t)r*8192 + 4096 + o] + bo;
      h = fmaxf(h, 0.f);
      int kc = o >> 6, wi = o & 63, slot = wi >> 3, rem = wi & 7;
      *(__bf16*)(H1b + (size_t)r*8192 + kc*128 + (((slot ^ (r & 7)) << 4) | (rem*2))) = (__bf16)h;
    }
}

// ---------------- h2 = S@R + T + b2 (no relu) ----------------------------------
__global__ __launch_bounds__(256) void k_h2(const float* __restrict__ RT,
                                            const float* __restrict__ St,
                                            const float* __restrict__ b2,
                                            float* __restrict__ h2){
  const int cch = blockIdx.x >> 2, nsp = blockIdx.x & 3;
  const int w = threadIdx.x >> 6, lane = threadIdx.x & 63;
  const int c = cch*64 + lane;
  const int nb = __builtin_amdgcn_readfirstlane(nsp*50 + w*13);
  const int ncnt = (w == 3) ? 11 : 13;
  float acc[13];
  #pragma unroll
  for (int i = 0; i < 13; i++) acc[i] = 0.f;
  for (int s = 0; s < 200; s++){
    float r = RT[(size_t)s*1024 + c];
    #pragma unroll
    for (int i = 0; i < 13; i++)
      if (i < ncnt) acc[i] = fmaf(St[s*200 + nb + i], r, acc[i]);
  }
  float bc = b2[c];
  #pragma unroll
  for (int i = 0; i < 13; i++)
    if (i < ncnt){
      int n = nb + i;
      h2[(size_t)n*512 + c] = acc[i] + RT[(size_t)n*1024 + 512 + c] + bc;
    }
}

// ---------------- classifier: out[512,10] = mlp(h2^T) --------------------------
__global__ __launch_bounds__(512) void k_cls(const float* __restrict__ h2,
    const float* __restrict__ Wc1, const float* __restrict__ bc1,
    const float* __restrict__ Wc2, const float* __restrict__ bc2,
    const float* __restrict__ Wc3, const float* __restrict__ bc3,
    float* __restrict__ out){
  __shared__ float zt[64*201];
  __shared__ float z1[64*101];
  __shared__ float z2[64*51];
  const int cb = blockIdx.x * 64;
  const int t = threadIdx.x;
  for (int idx = t; idx < 64*200; idx += 512){
    int n = idx >> 6, cl = idx & 63;
    zt[cl*201 + n] = h2[(size_t)n*512 + cb + cl];
  }
  __syncthreads();
  const int w = t >> 6, c = t & 63;
  {
    const int jb = __builtin_amdgcn_readfirstlane(w*13);
    const int jn = (w == 7) ? 9 : 13;
    float a[13];
    #pragma unroll
    for (int j = 0; j < 13; j++) a[j] = (j < jn) ? bc1[jb + j] : 0.f;
    for (int n = 0; n < 200; n++){
      float v = zt[c*201 + n];
      #pragma unroll
      for (int j = 0; j < 13; j++)
        if (j < jn) a[j] = fmaf(v, Wc1[(jb + j)*200 + n], a[j]);
    }
    #pragma unroll
    for (int j = 0; j < 13; j++)
      if (j < jn) z1[c*101 + jb + j] = fmaxf(a[j], 0.f);
  }
  __syncthreads();
  {
    const int jb = __builtin_amdgcn_readfirstlane(w*7);
    const int jn = (w == 7) ? 1 : 7;
    float a[7];
    #pragma unroll
    for (int j = 0; j < 7; j++) a[j] = (j < jn) ? bc2[jb + j] : 0.f;
    for (int n = 0; n < 100; n++){
      float v = z1[c*101 + n];
      #pragma unroll
      for (int j = 0; j < 7; j++)
        if (j < jn) a[j] = fmaf(v, Wc2[(jb + j)*100 + n], a[j]);
    }
    #pragma unroll
    for (int j = 0; j < 7; j++)
      if (j < jn) z2[c*51 + jb + j] = fmaxf(a[j], 0.f);
  }
  __syncthreads();
  if (w < 5){
    const int jb = __builtin_amdgcn_readfirstlane(w*2);
    float a[2] = { bc3[jb], bc3[jb + 1] };
    for (int n = 0; n < 50; n++){
      float v = z2[c*51 + n];
      a[0] = fmaf(v, Wc3[jb*50 + n], a[0]);
      a[1] = fmaf(v, Wc3[(jb + 1)*50 + n], a[1]);
    }
    out[(size_t)(cb + c)*10 + jb]     = a[0];
    out[(size_t)(cb + c)*10 + jb + 1] = a[1];
  }
}

// ---------------- host launch ---------------------------------------------------
extern "C" void kernel_launch(void* const* d_in, const int* in_sizes, int n_in,
                              void* d_out, int out_size, void* d_ws, size_t ws_size,
                              hipStream_t stream){
  (void)n_in; (void)out_size; (void)ws_size;
  const float* x   = (const float*)d_in[0];
  const int*   ei  = (const int*)  d_in[1];
  const float* ea  = (const float*)d_in[2];
  const float* W1l = (const float*)d_in[3];
  const float* W1r = (const float*)d_in[4];
  const float* b1  = (const float*)d_in[5];
  const float* W2l = (const float*)d_in[6];
  const float* W2r = (const float*)d_in[7];
  const float* b2  = (const float*)d_in[8];
  const float* Wc1 = (const float*)d_in[9];
  const float* bc1 = (const float*)d_in[10];
  const float* Wc2 = (const float*)d_in[11];
  const float* bc2 = (const float*)d_in[12];
  const float* Wc3 = (const float*)d_in[13];
  const float* bc3 = (const float*)d_in[14];
  float* out = (float*)d_out;
  char* ws = (char*)d_ws;
  const int E = in_sizes[1] / 2;

  constexpr size_t ST_OFF  = 0;
  constexpr size_t XB_OFF  = 262144;
  constexpr size_t CP1_OFF = XB_OFF + (size_t)256*16384*2;
  constexpr size_t PQ_OFF  = CP1_OFF + (size_t)8*224*8192*2;
  constexpr size_t H1B_OFF = PQ_OFF + (size_t)224*8192*4;
  constexpr size_t CP2_OFF = H1B_OFF + (size_t)256*4096*2;
  constexpr size_t RT_OFF  = CP2_OFF + (size_t)16*224*1024*2;
  constexpr size_t H2_OFF  = RT_OFF + (size_t)224*1024*4;

  float*          St  = (float*)(ws + ST_OFF);
  unsigned char*  Xb  = (unsigned char*)(ws + XB_OFF);
  unsigned short* Cp1 = (unsigned short*)(ws + CP1_OFF);
  float*          PQ  = (float*)(ws + PQ_OFF);
  unsigned char*  H1b = (unsigned char*)(ws + H1B_OFF);
  unsigned short* Cp2 = (unsigned short*)(ws + CP2_OFF);
  float*          RT  = (float*)(ws + RT_OFF);
  float*          h2  = (float*)(ws + H2_OFF);

  k_build_S<<<dim3(1),   dim3(1024), 0, stream>>>(ei, ea, E, St);
  k_xb     <<<dim3(256), dim3(256),  0, stream>>>(x, Xb);
  k_gemm<256, 8, 16384, 8192, 128><<<dim3(256), dim3(512), 0, stream>>>(Xb, W1l, W1r, Cp1);
  k_reduce<8> <<<dim3(256), dim3(256), 0, stream>>>(Cp1, PQ, 224*8192/8);
  k_h1     <<<dim3(256), dim3(256),  0, stream>>>(PQ, St, b1, H1b);
  k_gemm<128, 16, 4096, 1024, 64><<<dim3(128), dim3(512), 0, stream>>>(H1b, W2l, W2r, Cp2);
  k_reduce<16><<<dim3(64), dim3(256), 0, stream>>>(Cp2, RT, 224*1024/8);
  k_h2     <<<dim3(32),  dim3(256),  0, stream>>>(RT, St, b2, h2);
  k_cls    <<<dim3(8),   dim3(512),  0, stream>>>(h2, Wc1, bc1, Wc2, bc2, Wc3, bc3, out);
}